// Round 8
// baseline (451.907 us; speedup 1.0000x reference)
//
#include <hip/hip_runtime.h>
#include <stdint.h>

#define B_ 2
#define N_ 2048
#define C_ 512
#define H_ 8
#define D_ 64
#define TOPK_ 100
#define BN_ (B_*N_)
#define CAP_ 512

__device__ __forceinline__ int mbcnt64(unsigned long long m) {
  return __builtin_amdgcn_mbcnt_hi((unsigned)(m >> 32),
         __builtin_amdgcn_mbcnt_lo((unsigned)m, 0u));
}

// ---- EXACT f32 64x64 GEMM, BK=64, swizzled LDS ----
// NUMERICS CONTRACT: per output element, strictly k-ascending single-acc fmaf
// chain (k=0..511), bias added once at the end. Bit-identical to the passing
// r2/r6 runs. The top-k kept set depends on this — do not reorder.
// LDS layout: Xs[k][ m ^ (k & 60) ]  (XOR of k bits 2..5 into m bits 2..5).
// Writes: bank = (m ^ dk) % 32, 64 distinct words/wave -> 2-way (free).
// Reads: float4 stays contiguous (XOR only touches bits >=2); 2-way (free).
__global__ __launch_bounds__(256)
void gemm64(const float* __restrict__ X0, const float* __restrict__ X1,
            const float* __restrict__ X2,
            const float* __restrict__ W0, const float* __restrict__ W1,
            const float* __restrict__ W2,
            const float* __restrict__ b0, const float* __restrict__ b1,
            const float* __restrict__ b2,
            float* __restrict__ O0, float* __restrict__ O1,
            float* __restrict__ O2, int scatter)
{
  int z = blockIdx.z;
  const float* X = (z == 0) ? X0 : ((z == 1) ? X1 : X2);
  const float* W = (z == 0) ? W0 : ((z == 1) ? W1 : W2);
  const float* bs = (z == 0) ? b0 : ((z == 1) ? b1 : b2);
  float* O = (z == 0) ? O0 : ((z == 1) ? O1 : O2);

  __shared__ float Xs[64][64];
  __shared__ float Ws[64][64];

  int t = threadIdx.x;
  int tr = t >> 4, tc = t & 15;
  int m0 = blockIdx.x * 64, c0 = blockIdx.y * 64;

  float acc[4][4] = {};

  for (int k0 = 0; k0 < C_; k0 += 64) {
    #pragma unroll
    for (int j2 = 0; j2 < 4; ++j2) {
      int fid = t + j2 * 256;        // 0..1023
      int row = fid >> 4;            // 0..63
      int dk  = (fid & 15) << 2;     // 0..60, multiple of 4
      int co  = row ^ dk;            // swizzled column
      float4 xv = *(const float4*)(X + (size_t)(m0 + row) * C_ + k0 + dk);
      Xs[dk+0][co] = xv.x; Xs[dk+1][co] = xv.y; Xs[dk+2][co] = xv.z; Xs[dk+3][co] = xv.w;
      float4 wv = *(const float4*)(W + (size_t)(c0 + row) * C_ + k0 + dk);
      Ws[dk+0][co] = wv.x; Ws[dk+1][co] = wv.y; Ws[dk+2][co] = wv.z; Ws[dk+3][co] = wv.w;
    }
    __syncthreads();
    #pragma unroll 16
    for (int k = 0; k < 64; ++k) {
      int sw = k & 60;
      float4 a = *(const float4*)&Xs[k][(tr << 2) ^ sw];
      float4 b = *(const float4*)&Ws[k][(tc << 2) ^ sw];
      float ar[4] = {a.x, a.y, a.z, a.w};
      float br[4] = {b.x, b.y, b.z, b.w};
      #pragma unroll
      for (int i = 0; i < 4; ++i)
        #pragma unroll
        for (int j = 0; j < 4; ++j)
          acc[i][j] = fmaf(ar[i], br[j], acc[i][j]);
    }
    __syncthreads();
  }

  float bv[4];
  #pragma unroll
  for (int j = 0; j < 4; ++j) bv[j] = bs[c0 + (tc << 2) + j];

  #pragma unroll
  for (int i = 0; i < 4; ++i) {
    float4 o = make_float4(acc[i][0] + bv[0], acc[i][1] + bv[1],
                           acc[i][2] + bv[2], acc[i][3] + bv[3]);
    int m = m0 + (tr << 2) + i;
    if (scatter) {
      int bb = m >> 11;
      int tok = m & (N_ - 1);
      int h = blockIdx.y;            // c0 >> 6
      *(float4*)(O + (((size_t)(bb * H_ + h) * N_) + tok) * D_ + (tc << 2)) = o;
    } else {
      *(float4*)(O + (size_t)m * C_ + c0 + (tc << 2)) = o;
    }
  }
}

// ---- EXACT f32 QK^T: 128x128 tile, 8x8 micro (two 4-col groups 64 apart),
// swizzled LDS (row stride 128 words would be 8-way without it).
// Per-output chain: fmaf k=0..63 ascending, *0.125 at end — bit-identical
// to r6/r7. ----
__global__ __launch_bounds__(256)
void qk128(const float* __restrict__ qh, const float* __restrict__ kh,
           float* __restrict__ S, int slice0, int row0, int Rrows)
{
  int z = blockIdx.z;
  int slice = slice0 + z;
  const float* Q = qh + (size_t)slice * N_ * D_;
  const float* K = kh + (size_t)slice * N_ * D_;
  float* Sp = S + (size_t)z * Rrows * N_;

  __shared__ float Qs[32][128];
  __shared__ float Ks[32][128];

  int t = threadIdx.x;
  int tr = t >> 4, tc = t & 15;
  int n0 = blockIdx.x * 128, m0 = blockIdx.y * 128;

  float acc[2][2][4][4] = {};

  #pragma unroll
  for (int k0 = 0; k0 < D_; k0 += 32) {
    #pragma unroll
    for (int jj = 0; jj < 4; ++jj) {
      int fid = t + jj * 256;        // 0..1023
      int row = fid >> 3;            // 0..127
      int dk  = (fid & 7) << 2;      // 0..28
      int co  = row ^ (dk << 1);     // swizzle: k bits 2..4 -> m bits 3..5
      float4 qv = *(const float4*)(Q + (size_t)(row0 + n0 + row) * D_ + k0 + dk);
      Qs[dk+0][co] = qv.x; Qs[dk+1][co] = qv.y; Qs[dk+2][co] = qv.z; Qs[dk+3][co] = qv.w;
      float4 kv = *(const float4*)(K + (size_t)(m0 + row) * D_ + k0 + dk);
      Ks[dk+0][co] = kv.x; Ks[dk+1][co] = kv.y; Ks[dk+2][co] = kv.z; Ks[dk+3][co] = kv.w;
    }
    __syncthreads();
    #pragma unroll 8
    for (int k = 0; k < 32; ++k) {
      int sw = (k & 28) << 1;
      float a[2][4], b[2][4];
      *(float4*)&a[0][0] = *(const float4*)&Qs[k][(tr << 2) ^ sw];
      *(float4*)&a[1][0] = *(const float4*)&Qs[k][(64 + (tr << 2)) ^ sw];
      *(float4*)&b[0][0] = *(const float4*)&Ks[k][(tc << 2) ^ sw];
      *(float4*)&b[1][0] = *(const float4*)&Ks[k][(64 + (tc << 2)) ^ sw];
      #pragma unroll
      for (int ia = 0; ia < 2; ++ia)
        #pragma unroll
        for (int ib = 0; ib < 2; ++ib)
          #pragma unroll
          for (int i = 0; i < 4; ++i)
            #pragma unroll
            for (int j = 0; j < 4; ++j)
              acc[ia][ib][i][j] = fmaf(a[ia][i], b[ib][j], acc[ia][ib][i][j]);
    }
    __syncthreads();
  }

  const float scale = 0.125f;
  #pragma unroll
  for (int ia = 0; ia < 2; ++ia)
    #pragma unroll
    for (int i = 0; i < 4; ++i) {
      int n = n0 + ia*64 + (tr << 2) + i;
      #pragma unroll
      for (int ib = 0; ib < 2; ++ib) {
        float4 o = make_float4(acc[ia][ib][i][0] * scale, acc[ia][ib][i][1] * scale,
                               acc[ia][ib][i][2] * scale, acc[ia][ib][i][3] * scale);
        *(float4*)(Sp + (size_t)n * N_ + m0 + ib*64 + (tc << 2)) = o;
      }
    }
}

// ---- one wave per row: exact radix-select of 100th largest -> softmax over
// kept -> compaction -> gather-PV ----
__global__ __launch_bounds__(256)
void topk_softmax_pv(const float* __restrict__ S, const float* __restrict__ vh,
                     float* __restrict__ outp, int slice0, int row0, int log2R)
{
  __shared__ float wL[4][CAP_];
  __shared__ unsigned short iL[4][CAP_];

  int t = threadIdx.x;
  int wv = t >> 6;
  int lane = t & 63;
  int gr = blockIdx.x * 4 + wv;
  int s_local = gr >> log2R;
  int rrow = gr & ((1 << log2R) - 1);
  int slice = slice0 + s_local;
  int row = row0 + rrow;

  const float* Srow = S + ((size_t)gr) * N_;

  float x[32];
  #pragma unroll
  for (int i = 0; i < 8; ++i) {
    float4 v = *(const float4*)(Srow + i * 256 + lane * 4);
    x[i*4+0] = v.x; x[i*4+1] = v.y; x[i*4+2] = v.z; x[i*4+3] = v.w;
  }
  unsigned u[32];
  #pragma unroll
  for (int i = 0; i < 32; ++i) {
    unsigned bits = __float_as_uint(x[i]);
    u[i] = bits ^ ((unsigned)(((int)bits) >> 31) | 0x80000000u);
  }

  unsigned thr = 0u;
  for (int bit = 31; bit >= 0; --bit) {
    unsigned cand = thr | (1u << bit);
    int cnt = 0;
    #pragma unroll
    for (int i = 0; i < 32; ++i) {
      unsigned long long m = __ballot(u[i] >= cand);
      cnt += __popcll(m);
    }
    if (cnt >= TOPK_) {
      thr = cand;
      if (cnt == TOPK_) break;   // exact: kept set {u>=cand} is final
    }
  }

  float mx = -1e30f;
  #pragma unroll
  for (int i = 0; i < 32; ++i) mx = fmaxf(mx, x[i]);
  #pragma unroll
  for (int off = 32; off >= 1; off >>= 1) mx = fmaxf(mx, __shfl_xor(mx, off));

  float s = 0.f;
  #pragma unroll
  for (int i = 0; i < 32; ++i) {
    bool kp = (u[i] >= thr);
    float ev = kp ? __expf(x[i] - mx) : 0.f;
    x[i] = ev;
    s += ev;
  }
  #pragma unroll
  for (int off = 32; off >= 1; off >>= 1) s += __shfl_xor(s, off);
  float inv = 1.f / s;

  int base = 0;
  #pragma unroll
  for (int i = 0; i < 32; ++i) {
    bool kp = (u[i] >= thr);
    unsigned long long m = __ballot(kp);
    if (kp) {
      int pos = base + mbcnt64(m);
      if (pos < CAP_) {
        wL[wv][pos] = x[i] * inv;
        iL[wv][pos] = (unsigned short)((i >> 2) * 256 + lane * 4 + (i & 3));
      }
    }
    base += __popcll(m);
  }
  int total = base < CAP_ ? base : CAP_;

  // gather-PV, 8-deep ILP (post-select: reorder safe)
  const float* Vs = vh + (size_t)slice * N_ * D_;
  float a0=0.f,a1=0.f,a2=0.f,a3=0.f,a4=0.f,a5=0.f,a6=0.f,a7=0.f;
  int e = 0;
  for (; e + 8 <= total; e += 8) {
    float w0=wL[wv][e+0], w1=wL[wv][e+1], w2=wL[wv][e+2], w3=wL[wv][e+3];
    float w4=wL[wv][e+4], w5=wL[wv][e+5], w6=wL[wv][e+6], w7=wL[wv][e+7];
    int j0=iL[wv][e+0], j1=iL[wv][e+1], j2=iL[wv][e+2], j3=iL[wv][e+3];
    int j4=iL[wv][e+4], j5=iL[wv][e+5], j6=iL[wv][e+6], j7=iL[wv][e+7];
    float v0=Vs[(size_t)j0*D_+lane], v1=Vs[(size_t)j1*D_+lane];
    float v2=Vs[(size_t)j2*D_+lane], v3=Vs[(size_t)j3*D_+lane];
    float v4=Vs[(size_t)j4*D_+lane], v5=Vs[(size_t)j5*D_+lane];
    float v6=Vs[(size_t)j6*D_+lane], v7=Vs[(size_t)j7*D_+lane];
    a0 = fmaf(w0, v0, a0); a1 = fmaf(w1, v1, a1);
    a2 = fmaf(w2, v2, a2); a3 = fmaf(w3, v3, a3);
    a4 = fmaf(w4, v4, a4); a5 = fmaf(w5, v5, a5);
    a6 = fmaf(w6, v6, a6); a7 = fmaf(w7, v7, a7);
  }
  for (; e < total; ++e)
    a0 = fmaf(wL[wv][e], Vs[(size_t)iL[wv][e] * D_ + lane], a0);
  float acc = ((a0 + a1) + (a2 + a3)) + ((a4 + a5) + (a6 + a7));

  int b = slice >> 3;
  int h = slice & 7;
  outp[((size_t)(b * N_ + row)) * C_ + h * D_ + lane] = acc;
}

extern "C" void kernel_launch(void* const* d_in, const int* in_sizes, int n_in,
                              void* d_out, int out_size, void* d_ws, size_t ws_size,
                              hipStream_t stream) {
  const float* q  = (const float*)d_in[0];
  const float* k  = (const float*)d_in[1];
  const float* v  = (const float*)d_in[2];
  const float* Wq = (const float*)d_in[3];
  const float* bq = (const float*)d_in[4];
  const float* Wk = (const float*)d_in[5];
  const float* bk = (const float*)d_in[6];
  const float* Wv = (const float*)d_in[7];
  const float* bv = (const float*)d_in[8];
  const float* Wp = (const float*)d_in[9];
  const float* bp = (const float*)d_in[10];

  const size_t NB = (size_t)B_ * H_ * N_ * D_;   // 2,097,152 floats
  float* qh  = (float*)d_ws;
  float* kh  = qh + NB;
  float* vh  = kh + NB;
  float* pre = vh + NB;
  float* S   = pre + NB;

  size_t fixedB = 4 * NB * sizeof(float);              // 32 MB
  size_t sliceB = (size_t)N_ * N_ * sizeof(float);     // 16.78 MB
  size_t avail = (ws_size > fixedB) ? ws_size - fixedB : 0;

  int ns = 1, R = 2048;
  if      (avail >= 4 * sliceB) { ns = 4; R = 2048; }
  else if (avail >= 2 * sliceB) { ns = 2; R = 2048; }
  else if (avail >= 1 * sliceB) { ns = 1; R = 2048; }
  else if (avail >= sliceB / 2) { ns = 1; R = 1024; }
  else                          { ns = 1; R = 512;  }
  int log2R = (R == 2048) ? 11 : ((R == 1024) ? 10 : 9);

  dim3 blk(256);

  // Q/K/V projections: exact f32 chain, head-scatter
  gemm64<<<dim3(BN_/64, C_/64, 3), blk, 0, stream>>>(
      q, k, v, Wq, Wk, Wv, bq, bk, bv, qh, kh, vh, 1);

  for (int s0 = 0; s0 < B_ * H_; s0 += ns) {
    int cur = (B_ * H_ - s0) < ns ? (B_ * H_ - s0) : ns;
    for (int r0 = 0; r0 < N_; r0 += R) {
      qk128<<<dim3(R/128, N_/128, cur), blk, 0, stream>>>(qh, kh, S, s0, r0, R);
      topk_softmax_pv<<<dim3(cur * (R/4)), blk, 0, stream>>>(S, vh, pre, s0, r0, log2R);
    }
  }

  // final projection -> d_out
  gemm64<<<dim3(BN_/64, C_/64, 1), blk, 0, stream>>>(
      pre, pre, pre, Wp, Wp, Wp, bp, bp, bp,
      (float*)d_out, (float*)d_out, (float*)d_out, 0);
}